// Round 7
// baseline (606.450 us; speedup 1.0000x reference)
//
#include <hip/hip_runtime.h>
#include <math.h>

#define BTOT 131072
#define NBK 3
#define SS 16
#define NA 9
#define BAD 25      // SS+NA
#define STR 28      // padded LDS row stride (float4-aligned)
#define VD 128
#define CM 10
#define OUTD 51     // NBK*SS + 3
#define EPS 1e-8f

// ---- folded-weight image layout (float offsets); identical in ws and LDS ----
// every row padded to 4-float multiples, pads are ZERO
#define O_GQK  0        // 25 x 28  full Wq^T Wk
#define O_GQQ  700      // 25 x 28  lower-tri (off-diag x2) of Wq^T Wq
#define O_GKK  1400     // 25 x 28  lower-tri (off-diag x2) of Wk^T Wk
#define O_V1   2100     // 28: Wq^T bk
#define O_V2   2128     // 28: Wk^T bq
#define O_VQ   2156     // 28: Wq^T bq
#define O_VK   2184     // 28: Wk^T bk
#define O_C    2212     // c0=bq.bk, cq=bq.bq, ck=bk.bk, pad
#define O_M    2216     // 128 x 28: 2*(W1 @ Wv)   (x2 folded for tanh)
#define O_MB   5800     // 128:      2*(W1 @ bv + b1)
#define O_W2T  5928     // 128 x 16: W2 transposed [d][o]
#define O_B2   7976     // 16
#define O_WC1  7992     // 10 x 84: Wc1 repacked [m][i*28+f], f<25
#define O_BC1  8832     // 12
#define O_WC2  8844     // 3 x 12
#define O_BC2  8880     // 4
#define LDS_F  8884     // total floats (= 2221 float4)

__device__ __forceinline__ float fast_sigmoid(float x) {
    return __builtin_amdgcn_rcpf(1.0f + __expf(-x));
}

// one output element of the folded-weight image per thread
__global__ void prep_kernel(const float* __restrict__ Wq, const float* __restrict__ bq,
                            const float* __restrict__ Wk, const float* __restrict__ bk,
                            const float* __restrict__ Wv, const float* __restrict__ bv,
                            const float* __restrict__ W1, const float* __restrict__ b1,
                            const float* __restrict__ W2, const float* __restrict__ b2,
                            const float* __restrict__ Wc1, const float* __restrict__ bc1,
                            const float* __restrict__ Wc2, const float* __restrict__ bc2,
                            float* __restrict__ ws) {
    int idx = blockIdx.x * 256 + threadIdx.x;
    if (idx >= LDS_F) return;
    float val = 0.0f;
    if (idx < O_GQQ) {                       // Gqk full
        int e = idx / STR, f = idx % STR;
        if (f < BAD) {
            float s = 0.f;
            for (int d = 0; d < VD; ++d) s += Wq[d * BAD + e] * Wk[d * BAD + f];
            val = s;
        }
    } else if (idx < O_GKK) {                // Gqq lower-tri scaled
        int j = idx - O_GQQ; int e = j / STR, f = j % STR;
        if (f < BAD && f <= e) {
            float s = 0.f;
            for (int d = 0; d < VD; ++d) s += Wq[d * BAD + e] * Wq[d * BAD + f];
            val = (f == e) ? s : 2.0f * s;
        }
    } else if (idx < O_V1) {                 // Gkk lower-tri scaled
        int j = idx - O_GKK; int e = j / STR, f = j % STR;
        if (f < BAD && f <= e) {
            float s = 0.f;
            for (int d = 0; d < VD; ++d) s += Wk[d * BAD + e] * Wk[d * BAD + f];
            val = (f == e) ? s : 2.0f * s;
        }
    } else if (idx < O_V2) {
        int e = idx - O_V1;
        if (e < BAD) { float s = 0.f; for (int d = 0; d < VD; ++d) s += Wq[d * BAD + e] * bk[d]; val = s; }
    } else if (idx < O_VQ) {
        int e = idx - O_V2;
        if (e < BAD) { float s = 0.f; for (int d = 0; d < VD; ++d) s += Wk[d * BAD + e] * bq[d]; val = s; }
    } else if (idx < O_VK) {
        int e = idx - O_VQ;
        if (e < BAD) { float s = 0.f; for (int d = 0; d < VD; ++d) s += Wq[d * BAD + e] * bq[d]; val = s; }
    } else if (idx < O_C) {
        int e = idx - O_VK;
        if (e < BAD) { float s = 0.f; for (int d = 0; d < VD; ++d) s += Wk[d * BAD + e] * bk[d]; val = s; }
    } else if (idx < O_M) {
        int j = idx - O_C;
        if (j == 0) { float s = 0.f; for (int d = 0; d < VD; ++d) s += bq[d] * bk[d]; val = s; }
        else if (j == 1) { float s = 0.f; for (int d = 0; d < VD; ++d) s += bq[d] * bq[d]; val = s; }
        else if (j == 2) { float s = 0.f; for (int d = 0; d < VD; ++d) s += bk[d] * bk[d]; val = s; }
    } else if (idx < O_MB) {                 // 2 * W1 @ Wv
        int j = idx - O_M; int r = j / STR, c = j % STR;
        if (c < BAD) {
            float s = 0.f;
            for (int k = 0; k < VD; ++k) s += W1[r * VD + k] * Wv[k * BAD + c];
            val = 2.0f * s;
        }
    } else if (idx < O_W2T) {                // 2 * (W1 @ bv + b1)
        int d = idx - O_MB;
        float s = b1[d];
        for (int k = 0; k < VD; ++k) s += W1[d * VD + k] * bv[k];
        val = 2.0f * s;
    } else if (idx < O_B2) {
        int j = idx - O_W2T; int d = j / 16, o = j % 16;
        val = W2[o * VD + d];
    } else if (idx < O_WC1) {
        val = b2[idx - O_B2];
    } else if (idx < O_BC1) {                // Wc1 repacked [m][i*28+f]
        int j = idx - O_WC1; int m = j / 84; int r = j % 84; int i = r / STR; int f = r % STR;
        if (f < BAD) val = Wc1[m * (NBK * BAD) + i * BAD + f];
    } else if (idx < O_WC2) {
        int m = idx - O_BC1;
        if (m < CM) val = bc1[m];
    } else if (idx < O_BC2) {
        int j = idx - O_WC2; int o = j / 12, m = j % 12;
        if (m < CM) val = Wc2[o * CM + m];
    } else {
        int o = idx - O_BC2;
        if (o < 3) val = bc2[o];
    }
    ws[idx] = val;
}

// one thread per element. All ba[] indices compile-time (full unroll).
// __launch_bounds__(256, 1): min 1 wave/EU -> VGPR budget 512 (gfx950 unified
// file, no spill through ~450 [m08/m24]). Plain (256) targeted 2 waves/SIMD ->
// 256-VGPR hard budget -> ds_read results spilled to scratch/HBM (R6: 883 MB
// phantom traffic at exactly HBM-bound duration).
__global__ __launch_bounds__(256, 1) void main_kernel(
    const float* __restrict__ states, const float* __restrict__ action,
    const int* __restrict__ block_id,
    const float* __restrict__ ws, float* __restrict__ out) {
    __shared__ __align__(16) float lds[LDS_F];
    {
        const float4* s4 = (const float4*)ws;
        float4* d4 = (float4*)lds;
        for (int i = threadIdx.x; i < LDS_F / 4; i += 256) d4[i] = s4[i];
    }
    __syncthreads();

    int elem = blockIdx.x * 256 + threadIdx.x;

    const float* st = states + (long)elem * (NBK * SS);
    const float* ac = action + (long)elem * NA;
    const int* bid = block_id + (long)elem * NBK;

    // ---- build ba[3][25] ----
    float ba[NBK * BAD];
    #pragma unroll
    for (int i = 0; i < NBK; ++i) {
        const float4* s4 = (const float4*)(st + i * SS);  // 16B aligned: elem*192 + i*64
        #pragma unroll
        for (int w = 0; w < 4; ++w) {
            float4 v = s4[w];
            ba[i * BAD + w * 4 + 0] = v.x;
            ba[i * BAD + w * 4 + 1] = v.y;
            ba[i * BAD + w * 4 + 2] = v.z;
            ba[i * BAD + w * 4 + 3] = v.w;
        }
        bool sel = (bid[i] == 1);
        #pragma unroll
        for (int c = 0; c < NA; ++c)
            ba[i * BAD + SS + c] = sel ? ac[c] : -1.0f;
    }

    // ---- confidence MLP ----
    float conf0, conf1, conf2;
    {
        float hm[CM];
        #pragma unroll
        for (int m = 0; m < CM; ++m) {
            float s = lds[O_BC1 + m];
            #pragma unroll
            for (int i = 0; i < NBK; ++i)
                #pragma unroll
                for (int f = 0; f < BAD; ++f)
                    s += lds[O_WC1 + m * 84 + i * STR + f] * ba[i * BAD + f];
            hm[m] = fast_sigmoid(s);
        }
        float c[3];
        #pragma unroll
        for (int o = 0; o < 3; ++o) {
            float s = lds[O_BC2 + o];
            #pragma unroll
            for (int m = 0; m < CM; ++m) s += lds[O_WC2 + o * 12 + m] * hm[m];
            c[o] = fast_sigmoid(s);
        }
        conf0 = c[0]; conf1 = c[1]; conf2 = c[2];
    }

    // ---- linear score terms ----
    float s1[NBK], s2[NBK], dq[NBK], dk[NBK];
    #pragma unroll
    for (int p = 0; p < NBK; ++p) {
        float a1 = 0.f, a2 = 0.f, aq = 0.f, ak = 0.f;
        #pragma unroll
        for (int e = 0; e < BAD; ++e) {
            float b = ba[p * BAD + e];
            a1 += lds[O_V1 + e] * b;
            a2 += lds[O_V2 + e] * b;
            aq += lds[O_VQ + e] * b;
            ak += lds[O_VK + e] * b;
        }
        s1[p] = a1; s2[p] = a2; dq[p] = aq; dk[p] = ak;
    }
    float c0 = lds[O_C + 0], cq = lds[O_C + 1], ck = lds[O_C + 2];

    // ---- bilinear numerators: FULL unroll (compile-time ba indices) ----
    float num[NBK][NBK] = {{0.f,0.f,0.f},{0.f,0.f,0.f},{0.f,0.f,0.f}};
    #pragma unroll
    for (int e = 0; e < BAD; ++e) {
        float t0 = 0.f, t1 = 0.f, t2 = 0.f;
        #pragma unroll
        for (int f = 0; f < BAD; ++f) {
            float g = lds[O_GQK + e * STR + f];
            t0 += g * ba[0 * BAD + f];
            t1 += g * ba[1 * BAD + f];
            t2 += g * ba[2 * BAD + f];
        }
        #pragma unroll
        for (int i = 0; i < NBK; ++i) {
            float be = ba[i * BAD + e];
            num[i][0] += be * t0;
            num[i][1] += be * t1;
            num[i][2] += be * t2;
        }
    }

    // ---- quadratic forms via scaled lower triangles: FULL unroll ----
    float qn2[NBK] = {0.f, 0.f, 0.f}, kn2[NBK] = {0.f, 0.f, 0.f};
    #pragma unroll
    for (int e = 0; e < BAD; ++e) {
        float pq0 = 0.f, pq1 = 0.f, pq2 = 0.f;
        float pk0 = 0.f, pk1 = 0.f, pk2 = 0.f;
        #pragma unroll
        for (int f = 0; f <= e; ++f) {
            float gq = lds[O_GQQ + e * STR + f];
            float gk = lds[O_GKK + e * STR + f];
            float b0 = ba[0 * BAD + f], b1v = ba[1 * BAD + f], b2v = ba[2 * BAD + f];
            pq0 += gq * b0; pq1 += gq * b1v; pq2 += gq * b2v;
            pk0 += gk * b0; pk1 += gk * b1v; pk2 += gk * b2v;
        }
        qn2[0] += ba[0 * BAD + e] * pq0;
        qn2[1] += ba[1 * BAD + e] * pq1;
        qn2[2] += ba[2 * BAD + e] * pq2;
        kn2[0] += ba[0 * BAD + e] * pk0;
        kn2[1] += ba[1 * BAD + e] * pk1;
        kn2[2] += ba[2 * BAD + e] * pk2;
    }
    #pragma unroll
    for (int p = 0; p < NBK; ++p) {
        qn2[p] += 2.0f * dq[p] + cq;
        kn2[p] += 2.0f * dk[p] + ck;
    }

    // ---- softmax over j ----
    float att[NBK][NBK];
    {
        float kn[NBK];
        #pragma unroll
        for (int j = 0; j < NBK; ++j) kn[j] = __builtin_amdgcn_sqrtf(fmaxf(kn2[j], 0.0f));
        #pragma unroll
        for (int i = 0; i < NBK; ++i) {
            float qn = __builtin_amdgcn_sqrtf(fmaxf(qn2[i], 0.0f));
            float dv[NBK];
            #pragma unroll
            for (int j = 0; j < NBK; ++j)
                dv[j] = (num[i][j] + s1[i] + s2[j] + c0) *
                        __builtin_amdgcn_rcpf(fmaxf(qn * kn[j], EPS));
            float mx = fmaxf(dv[0], fmaxf(dv[1], dv[2]));
            float e0 = __expf(dv[0] - mx);
            float e1 = __expf(dv[1] - mx);
            float e2 = __expf(dv[2] - mx);
            float inv = __builtin_amdgcn_rcpf(e0 + e1 + e2);
            att[i][0] = e0 * inv;
            att[i][1] = e1 * inv;
            att[i][2] = e2 * inv;
        }
    }

    // ---- r2 init from base (states) + b2, before ba overwrite ----
    float r2[NBK * SS];
    #pragma unroll
    for (int i = 0; i < NBK; ++i)
        #pragma unroll
        for (int o = 0; o < SS; ++o) r2[i * SS + o] = ba[i * BAD + o] + lds[O_B2 + o];

    // ---- a_tilde_i = sum_j att[i][j] * ba_j (in place) ----
    #pragma unroll
    for (int e = 0; e < BAD; ++e) {
        float b0 = ba[0 * BAD + e], b1v = ba[1 * BAD + e], b2v = ba[2 * BAD + e];
        ba[0 * BAD + e] = att[0][0] * b0 + att[0][1] * b1v + att[0][2] * b2v;
        ba[1 * BAD + e] = att[1][0] * b0 + att[1][1] * b1v + att[1][2] * b2v;
        ba[2 * BAD + e] = att[2][0] * b0 + att[2][1] * b1v + att[2][2] * b2v;
    }

    // ---- main VD loop (d runtime is fine: only LDS is dynamically indexed) ----
    #pragma unroll 2
    for (int d = 0; d < VD; ++d) {
        float m0 = lds[O_MB + d];
        float acc0 = m0, acc1 = m0, acc2 = m0;
        #pragma unroll
        for (int e = 0; e < BAD; ++e) {
            float m = lds[O_M + d * STR + e];
            acc0 += m * ba[0 * BAD + e];
            acc1 += m * ba[1 * BAD + e];
            acc2 += m * ba[2 * BAD + e];
        }
        // tanh(x) = 1 - 2/(1+exp(2x)); acc already = 2x (M,mb doubled in prep)
        float r10 = fmaf(-2.0f, __builtin_amdgcn_rcpf(1.0f + __expf(acc0)), 1.0f);
        float r11 = fmaf(-2.0f, __builtin_amdgcn_rcpf(1.0f + __expf(acc1)), 1.0f);
        float r12 = fmaf(-2.0f, __builtin_amdgcn_rcpf(1.0f + __expf(acc2)), 1.0f);
        #pragma unroll
        for (int o = 0; o < SS; ++o) {
            float w = lds[O_W2T + d * 16 + o];
            r2[0 * SS + o] += r10 * w;
            r2[1 * SS + o] += r11 * w;
            r2[2 * SS + o] += r12 * w;
        }
    }

    // ---- store ----
    float* op = out + (long)elem * OUTD;
    #pragma unroll
    for (int k = 0; k < NBK * SS; ++k) op[k] = r2[k];
    op[48] = conf0;
    op[49] = conf1;
    op[50] = conf2;
}

extern "C" void kernel_launch(void* const* d_in, const int* in_sizes, int n_in,
                              void* d_out, int out_size, void* d_ws, size_t ws_size,
                              hipStream_t stream) {
    const float* states = (const float*)d_in[0];
    const float* action = (const float*)d_in[1];
    const int* block_id = (const int*)d_in[2];
    const float* Wq = (const float*)d_in[3];
    const float* bq = (const float*)d_in[4];
    const float* Wk = (const float*)d_in[5];
    const float* bk = (const float*)d_in[6];
    const float* Wv = (const float*)d_in[7];
    const float* bv = (const float*)d_in[8];
    const float* W1 = (const float*)d_in[9];
    const float* b1 = (const float*)d_in[10];
    const float* W2 = (const float*)d_in[11];
    const float* b2 = (const float*)d_in[12];
    const float* Wc1 = (const float*)d_in[13];
    const float* bc1 = (const float*)d_in[14];
    const float* Wc2 = (const float*)d_in[15];
    const float* bc2 = (const float*)d_in[16];
    float* out = (float*)d_out;
    float* ws = (float*)d_ws;

    hipLaunchKernelGGL(prep_kernel, dim3((LDS_F + 255) / 256), dim3(256), 0, stream,
                       Wq, bq, Wk, bk, Wv, bv, W1, b1, W2, b2, Wc1, bc1, Wc2, bc2, ws);
    hipLaunchKernelGGL(main_kernel, dim3(BTOT / 256), dim3(256), 0, stream,
                       states, action, block_id, ws, out);
}

// Round 8
// 351.901 us; speedup vs baseline: 1.7234x; 1.7234x over previous
//
#include <hip/hip_runtime.h>
#include <math.h>

#define BTOT 131072
#define NBK 3
#define SS 16
#define NA 9
#define BAD 25      // SS+NA
#define STR 28      // padded row stride in the weight image
#define VD 128
#define CM 10
#define OUTD 51     // NBK*SS + 3
#define EPS 1e-8f

// ---- folded-weight image layout (float offsets) in ws (global) ----
// rows padded to 4-float multiples, pads are ZERO
#define O_GQK  0        // 25 x 28  full Wq^T Wk
#define O_GQQ  700      // 25 x 28  lower-tri (off-diag x2) of Wq^T Wq
#define O_GKK  1400     // 25 x 28  lower-tri (off-diag x2) of Wk^T Wk
#define O_V1   2100     // 28: Wq^T bk
#define O_V2   2128     // 28: Wk^T bq
#define O_VQ   2156     // 28: Wq^T bq
#define O_VK   2184     // 28: Wk^T bk
#define O_C    2212     // c0=bq.bk, cq=bq.bq, ck=bk.bk, pad
#define O_M    2216     // 128 x 28: 2*(W1 @ Wv)   (x2 folded for tanh)
#define O_MB   5800     // 128:      2*(W1 @ bv + b1)
#define O_W2T  5928     // 128 x 16: W2 transposed [d][o]
#define O_B2   7976     // 16
#define O_WC1  7992     // 10 x 84: Wc1 repacked [m][i*28+f], f<25
#define O_BC1  8832     // 12
#define O_WC2  8844     // 3 x 12
#define O_BC2  8880     // 4
#define LDS_F  8884

__device__ __forceinline__ float fast_sigmoid(float x) {
    return __builtin_amdgcn_rcpf(1.0f + __expf(-x));
}

// one output element of the folded-weight image per thread
__global__ void prep_kernel(const float* __restrict__ Wq, const float* __restrict__ bq,
                            const float* __restrict__ Wk, const float* __restrict__ bk,
                            const float* __restrict__ Wv, const float* __restrict__ bv,
                            const float* __restrict__ W1, const float* __restrict__ b1,
                            const float* __restrict__ W2, const float* __restrict__ b2,
                            const float* __restrict__ Wc1, const float* __restrict__ bc1,
                            const float* __restrict__ Wc2, const float* __restrict__ bc2,
                            float* __restrict__ ws) {
    int idx = blockIdx.x * 256 + threadIdx.x;
    if (idx >= LDS_F) return;
    float val = 0.0f;
    if (idx < O_GQQ) {                       // Gqk full
        int e = idx / STR, f = idx % STR;
        if (f < BAD) {
            float s = 0.f;
            for (int d = 0; d < VD; ++d) s += Wq[d * BAD + e] * Wk[d * BAD + f];
            val = s;
        }
    } else if (idx < O_GKK) {                // Gqq lower-tri scaled
        int j = idx - O_GQQ; int e = j / STR, f = j % STR;
        if (f < BAD && f <= e) {
            float s = 0.f;
            for (int d = 0; d < VD; ++d) s += Wq[d * BAD + e] * Wq[d * BAD + f];
            val = (f == e) ? s : 2.0f * s;
        }
    } else if (idx < O_V1) {                 // Gkk lower-tri scaled
        int j = idx - O_GKK; int e = j / STR, f = j % STR;
        if (f < BAD && f <= e) {
            float s = 0.f;
            for (int d = 0; d < VD; ++d) s += Wk[d * BAD + e] * Wk[d * BAD + f];
            val = (f == e) ? s : 2.0f * s;
        }
    } else if (idx < O_V2) {
        int e = idx - O_V1;
        if (e < BAD) { float s = 0.f; for (int d = 0; d < VD; ++d) s += Wq[d * BAD + e] * bk[d]; val = s; }
    } else if (idx < O_VQ) {
        int e = idx - O_V2;
        if (e < BAD) { float s = 0.f; for (int d = 0; d < VD; ++d) s += Wk[d * BAD + e] * bq[d]; val = s; }
    } else if (idx < O_VK) {
        int e = idx - O_VQ;
        if (e < BAD) { float s = 0.f; for (int d = 0; d < VD; ++d) s += Wq[d * BAD + e] * bq[d]; val = s; }
    } else if (idx < O_C) {
        int e = idx - O_VK;
        if (e < BAD) { float s = 0.f; for (int d = 0; d < VD; ++d) s += Wk[d * BAD + e] * bk[d]; val = s; }
    } else if (idx < O_M) {
        int j = idx - O_C;
        if (j == 0) { float s = 0.f; for (int d = 0; d < VD; ++d) s += bq[d] * bk[d]; val = s; }
        else if (j == 1) { float s = 0.f; for (int d = 0; d < VD; ++d) s += bq[d] * bq[d]; val = s; }
        else if (j == 2) { float s = 0.f; for (int d = 0; d < VD; ++d) s += bk[d] * bk[d]; val = s; }
    } else if (idx < O_MB) {                 // 2 * W1 @ Wv
        int j = idx - O_M; int r = j / STR, c = j % STR;
        if (c < BAD) {
            float s = 0.f;
            for (int k = 0; k < VD; ++k) s += W1[r * VD + k] * Wv[k * BAD + c];
            val = 2.0f * s;
        }
    } else if (idx < O_W2T) {                // 2 * (W1 @ bv + b1)
        int d = idx - O_MB;
        float s = b1[d];
        for (int k = 0; k < VD; ++k) s += W1[d * VD + k] * bv[k];
        val = 2.0f * s;
    } else if (idx < O_B2) {
        int j = idx - O_W2T; int d = j / 16, o = j % 16;
        val = W2[o * VD + d];
    } else if (idx < O_WC1) {
        val = b2[idx - O_B2];
    } else if (idx < O_BC1) {                // Wc1 repacked [m][i*28+f]
        int j = idx - O_WC1; int m = j / 84; int r = j % 84; int i = r / STR; int f = r % STR;
        if (f < BAD) val = Wc1[m * (NBK * BAD) + i * BAD + f];
    } else if (idx < O_WC2) {
        int m = idx - O_BC1;
        if (m < CM) val = bc1[m];
    } else if (idx < O_BC2) {
        int j = idx - O_WC2; int o = j / 12, m = j % 12;
        if (m < CM) val = Wc2[o * CM + m];
    } else {
        int o = idx - O_BC2;
        if (o < 3) val = bc2[o];
    }
    ws[idx] = val;
}

// one thread per element. Weights read DIRECTLY FROM GLOBAL at wave-uniform
// addresses -> compiler emits s_load -> weights live in SGPRs (zero VGPR
// cost). This is the only spill-free weight channel: LDS staging (R3-R7)
// forces ds_read results into VGPRs and blows the 256 architectural VGPR
// ceiling -> scratch spill -> HBM-bound. R1 proved this path: VGPR=160,
// hbm_bytes ideal. No __shared__ in this kernel at all.
__global__ __launch_bounds__(256) void main_kernel(
    const float* __restrict__ states, const float* __restrict__ action,
    const int* __restrict__ block_id,
    const float* __restrict__ ws, float* __restrict__ out) {
    int elem = blockIdx.x * 256 + threadIdx.x;

    const float* st = states + (long)elem * (NBK * SS);
    const float* ac = action + (long)elem * NA;
    const int* bid = block_id + (long)elem * NBK;

    // ---- build ba[3][25] (all indices compile-time) ----
    float ba[NBK * BAD];
    #pragma unroll
    for (int i = 0; i < NBK; ++i) {
        const float4* s4 = (const float4*)(st + i * SS);  // 16B aligned
        #pragma unroll
        for (int w = 0; w < 4; ++w) {
            float4 v = s4[w];
            ba[i * BAD + w * 4 + 0] = v.x;
            ba[i * BAD + w * 4 + 1] = v.y;
            ba[i * BAD + w * 4 + 2] = v.z;
            ba[i * BAD + w * 4 + 3] = v.w;
        }
        bool sel = (bid[i] == 1);
        #pragma unroll
        for (int c = 0; c < NA; ++c)
            ba[i * BAD + SS + c] = sel ? ac[c] : -1.0f;
    }

    // ---- confidence MLP ----
    float conf0, conf1, conf2;
    {
        float hm[CM];
        #pragma unroll
        for (int m = 0; m < CM; ++m) {
            float s = ws[O_BC1 + m];
            #pragma unroll
            for (int i = 0; i < NBK; ++i)
                #pragma unroll
                for (int f = 0; f < BAD; ++f)
                    s += ws[O_WC1 + m * 84 + i * STR + f] * ba[i * BAD + f];
            hm[m] = fast_sigmoid(s);
        }
        float c[3];
        #pragma unroll
        for (int o = 0; o < 3; ++o) {
            float s = ws[O_BC2 + o];
            #pragma unroll
            for (int m = 0; m < CM; ++m) s += ws[O_WC2 + o * 12 + m] * hm[m];
            c[o] = fast_sigmoid(s);
        }
        conf0 = c[0]; conf1 = c[1]; conf2 = c[2];
    }

    // ---- linear score terms ----
    float s1[NBK], s2[NBK], dq[NBK], dk[NBK];
    #pragma unroll
    for (int p = 0; p < NBK; ++p) {
        float a1 = 0.f, a2 = 0.f, aq = 0.f, ak = 0.f;
        #pragma unroll
        for (int e = 0; e < BAD; ++e) {
            float b = ba[p * BAD + e];
            a1 += ws[O_V1 + e] * b;
            a2 += ws[O_V2 + e] * b;
            aq += ws[O_VQ + e] * b;
            ak += ws[O_VK + e] * b;
        }
        s1[p] = a1; s2[p] = a2; dq[p] = aq; dk[p] = ak;
    }
    float c0 = ws[O_C + 0], cq = ws[O_C + 1], ck = ws[O_C + 2];

    // ---- bilinear numerators ----
    float num[NBK][NBK] = {{0.f,0.f,0.f},{0.f,0.f,0.f},{0.f,0.f,0.f}};
    #pragma unroll
    for (int e = 0; e < BAD; ++e) {
        float t0 = 0.f, t1 = 0.f, t2 = 0.f;
        #pragma unroll
        for (int f = 0; f < BAD; ++f) {
            float g = ws[O_GQK + e * STR + f];
            t0 += g * ba[0 * BAD + f];
            t1 += g * ba[1 * BAD + f];
            t2 += g * ba[2 * BAD + f];
        }
        #pragma unroll
        for (int i = 0; i < NBK; ++i) {
            float be = ba[i * BAD + e];
            num[i][0] += be * t0;
            num[i][1] += be * t1;
            num[i][2] += be * t2;
        }
    }

    // ---- quadratic forms via scaled lower triangles ----
    float qn2[NBK] = {0.f, 0.f, 0.f}, kn2[NBK] = {0.f, 0.f, 0.f};
    #pragma unroll
    for (int e = 0; e < BAD; ++e) {
        float pq0 = 0.f, pq1 = 0.f, pq2 = 0.f;
        float pk0 = 0.f, pk1 = 0.f, pk2 = 0.f;
        #pragma unroll
        for (int f = 0; f <= e; ++f) {
            float gq = ws[O_GQQ + e * STR + f];
            float gk = ws[O_GKK + e * STR + f];
            float b0 = ba[0 * BAD + f], b1v = ba[1 * BAD + f], b2v = ba[2 * BAD + f];
            pq0 += gq * b0; pq1 += gq * b1v; pq2 += gq * b2v;
            pk0 += gk * b0; pk1 += gk * b1v; pk2 += gk * b2v;
        }
        qn2[0] += ba[0 * BAD + e] * pq0;
        qn2[1] += ba[1 * BAD + e] * pq1;
        qn2[2] += ba[2 * BAD + e] * pq2;
        kn2[0] += ba[0 * BAD + e] * pk0;
        kn2[1] += ba[1 * BAD + e] * pk1;
        kn2[2] += ba[2 * BAD + e] * pk2;
    }
    #pragma unroll
    for (int p = 0; p < NBK; ++p) {
        qn2[p] += 2.0f * dq[p] + cq;
        kn2[p] += 2.0f * dk[p] + ck;
    }

    // ---- softmax over j ----
    float att[NBK][NBK];
    {
        float kn[NBK];
        #pragma unroll
        for (int j = 0; j < NBK; ++j) kn[j] = __builtin_amdgcn_sqrtf(fmaxf(kn2[j], 0.0f));
        #pragma unroll
        for (int i = 0; i < NBK; ++i) {
            float qn = __builtin_amdgcn_sqrtf(fmaxf(qn2[i], 0.0f));
            float dv[NBK];
            #pragma unroll
            for (int j = 0; j < NBK; ++j)
                dv[j] = (num[i][j] + s1[i] + s2[j] + c0) *
                        __builtin_amdgcn_rcpf(fmaxf(qn * kn[j], EPS));
            float mx = fmaxf(dv[0], fmaxf(dv[1], dv[2]));
            float e0 = __expf(dv[0] - mx);
            float e1 = __expf(dv[1] - mx);
            float e2 = __expf(dv[2] - mx);
            float inv = __builtin_amdgcn_rcpf(e0 + e1 + e2);
            att[i][0] = e0 * inv;
            att[i][1] = e1 * inv;
            att[i][2] = e2 * inv;
        }
    }

    // ---- r2 init from base (states) + b2, before ba overwrite ----
    float r2[NBK * SS];
    #pragma unroll
    for (int i = 0; i < NBK; ++i)
        #pragma unroll
        for (int o = 0; o < SS; ++o) r2[i * SS + o] = ba[i * BAD + o] + ws[O_B2 + o];

    // ---- a_tilde_i = sum_j att[i][j] * ba_j (in place) ----
    #pragma unroll
    for (int e = 0; e < BAD; ++e) {
        float b0 = ba[0 * BAD + e], b1v = ba[1 * BAD + e], b2v = ba[2 * BAD + e];
        ba[0 * BAD + e] = att[0][0] * b0 + att[0][1] * b1v + att[0][2] * b2v;
        ba[1 * BAD + e] = att[1][0] * b0 + att[1][1] * b1v + att[1][2] * b2v;
        ba[2 * BAD + e] = att[2][0] * b0 + att[2][1] * b1v + att[2][2] * b2v;
    }

    // ---- main VD loop: weights via s_load (uniform), x2 unroll for ILP ----
    #pragma unroll 2
    for (int d = 0; d < VD; ++d) {
        float m0 = ws[O_MB + d];
        float acc0 = m0, acc1 = m0, acc2 = m0;
        #pragma unroll
        for (int e = 0; e < BAD; ++e) {
            float m = ws[O_M + d * STR + e];
            acc0 += m * ba[0 * BAD + e];
            acc1 += m * ba[1 * BAD + e];
            acc2 += m * ba[2 * BAD + e];
        }
        // tanh(x) = 1 - 2/(1+exp(2x)); acc already = 2x (M,mb doubled in prep)
        float r10 = fmaf(-2.0f, __builtin_amdgcn_rcpf(1.0f + __expf(acc0)), 1.0f);
        float r11 = fmaf(-2.0f, __builtin_amdgcn_rcpf(1.0f + __expf(acc1)), 1.0f);
        float r12 = fmaf(-2.0f, __builtin_amdgcn_rcpf(1.0f + __expf(acc2)), 1.0f);
        #pragma unroll
        for (int o = 0; o < SS; ++o) {
            float w = ws[O_W2T + d * 16 + o];
            r2[0 * SS + o] += r10 * w;
            r2[1 * SS + o] += r11 * w;
            r2[2 * SS + o] += r12 * w;
        }
    }

    // ---- store ----
    float* op = out + (long)elem * OUTD;
    #pragma unroll
    for (int k = 0; k < NBK * SS; ++k) op[k] = r2[k];
    op[48] = conf0;
    op[49] = conf1;
    op[50] = conf2;
}

extern "C" void kernel_launch(void* const* d_in, const int* in_sizes, int n_in,
                              void* d_out, int out_size, void* d_ws, size_t ws_size,
                              hipStream_t stream) {
    const float* states = (const float*)d_in[0];
    const float* action = (const float*)d_in[1];
    const int* block_id = (const int*)d_in[2];
    const float* Wq = (const float*)d_in[3];
    const float* bq = (const float*)d_in[4];
    const float* Wk = (const float*)d_in[5];
    const float* bk = (const float*)d_in[6];
    const float* Wv = (const float*)d_in[7];
    const float* bv = (const float*)d_in[8];
    const float* W1 = (const float*)d_in[9];
    const float* b1 = (const float*)d_in[10];
    const float* W2 = (const float*)d_in[11];
    const float* b2 = (const float*)d_in[12];
    const float* Wc1 = (const float*)d_in[13];
    const float* bc1 = (const float*)d_in[14];
    const float* Wc2 = (const float*)d_in[15];
    const float* bc2 = (const float*)d_in[16];
    float* out = (float*)d_out;
    float* ws = (float*)d_ws;

    hipLaunchKernelGGL(prep_kernel, dim3((LDS_F + 255) / 256), dim3(256), 0, stream,
                       Wq, bq, Wk, bk, Wv, bv, W1, b1, W2, b2, Wc1, bc1, Wc2, bc2, ws);
    hipLaunchKernelGGL(main_kernel, dim3(BTOT / 256), dim3(256), 0, stream,
                       states, action, block_id, ws, out);
}

// Round 9
// 233.598 us; speedup vs baseline: 2.5961x; 1.5064x over previous
//
#include <hip/hip_runtime.h>
#include <math.h>

#define BTOT 131072
#define NBK 3
#define SS 16
#define NA 9
#define BAD 25      // SS+NA
#define STR 28      // padded row stride in the fp32 weight image
#define VD 128
#define CM 10
#define OUTD 51     // NBK*SS + 3
#define EPS 1e-8f

// ---- fp32 folded-weight image (float offsets in ws) ----
#define O_GQK  0        // 25 x 28  full Wq^T Wk
#define O_GQQ  700      // 25 x 28  lower-tri (off-diag x2) of Wq^T Wq
#define O_GKK  1400     // 25 x 28  lower-tri (off-diag x2) of Wk^T Wk
#define O_V1   2100     // 28: Wq^T bk
#define O_V2   2128     // 28: Wk^T bq
#define O_VQ   2156     // 28: Wq^T bq
#define O_VK   2184     // 28: Wk^T bk
#define O_C    2212     // c0, cq, ck, pad
#define O_M    2216     // 128 x 28 fp32 (unused by main now; kept for layout)
#define O_MB   5800     // 128 (unused by main now)
#define O_W2T  5928     // 128 x 16: W2 transposed [d][o] fp32
#define O_B2   7976     // 16
#define O_WC1  7992     // 10 x 84
#define O_BC1  8832     // 12
#define O_WC2  8844     // 3 x 12
#define O_BC2  8880     // 4
#define LDS_F  8884
// ---- bf16 MFMA-packed B-fragments appended after the fp32 image ----
// pkM: 8 n-tiles x 64 lanes x 8 bf16  (B[k][n] for GEMM1; k=25 row = mb bias)
// pkW2: 4 k-tiles x 64 lanes x 8 bf16 (B[k][n] for GEMM2)
#define O_PKM  LDS_F          // float offset; 4096 ushorts = 2048 floats
#define O_PKW2 (LDS_F + 2048) // 2048 ushorts = 1024 floats
#define PKM_N  4096
#define PKW2_N 2048
#define TOT_IDX (LDS_F + PKM_N + PKW2_N)

typedef __attribute__((ext_vector_type(8))) short short8;
typedef __attribute__((ext_vector_type(4))) float floatx4;

__device__ __forceinline__ float fast_sigmoid(float x) {
    return __builtin_amdgcn_rcpf(1.0f + __expf(-x));
}

__device__ __forceinline__ unsigned short f2bf(float f) {
    unsigned int u = __float_as_uint(f);
    u += 0x7FFFu + ((u >> 16) & 1u);   // round-to-nearest-even
    return (unsigned short)(u >> 16);
}

__global__ void prep_kernel(const float* __restrict__ Wq, const float* __restrict__ bq,
                            const float* __restrict__ Wk, const float* __restrict__ bk,
                            const float* __restrict__ Wv, const float* __restrict__ bv,
                            const float* __restrict__ W1, const float* __restrict__ b1,
                            const float* __restrict__ W2, const float* __restrict__ b2,
                            const float* __restrict__ Wc1, const float* __restrict__ bc1,
                            const float* __restrict__ Wc2, const float* __restrict__ bc2,
                            float* __restrict__ ws) {
    int idx = blockIdx.x * 256 + threadIdx.x;
    if (idx >= TOT_IDX) return;

    if (idx >= LDS_F) {
        int p = idx - LDS_F;
        if (p < PKM_N) {
            // GEMM1 B-frag: B[k][n], n = tile*16 + (lane&15), k = (lane>>4)*8 + j
            int tile = p >> 9, lane = (p >> 3) & 63, j = p & 7;
            int n = tile * 16 + (lane & 15);
            int k = ((lane >> 4) << 3) + j;
            float val = 0.0f;
            if (k < BAD) {
                float s = 0.f;
                for (int c = 0; c < VD; ++c) s += W1[n * VD + c] * Wv[c * BAD + k];
                val = 2.0f * s;                       // x2 folded for tanh
            } else if (k == BAD) {                    // bias row (a_tilde col 25 = 1)
                float s = b1[n];
                for (int c = 0; c < VD; ++c) s += W1[n * VD + c] * bv[c];
                val = 2.0f * s;
            }
            ((unsigned short*)(ws + O_PKM))[p] = f2bf(val);
        } else {
            // GEMM2 B-frag: B[k][o], o = lane&15, k = kt*32 + (lane>>4)*8 + j
            int q2 = p - PKM_N;
            int kt = q2 >> 9, lane = (q2 >> 3) & 63, j = q2 & 7;
            int o = lane & 15;
            int k = kt * 32 + ((lane >> 4) << 3) + j;
            ((unsigned short*)(ws + O_PKW2))[q2] = f2bf(W2[o * VD + k]);
        }
        return;
    }

    float val = 0.0f;
    if (idx < O_GQQ) {
        int e = idx / STR, f = idx % STR;
        if (f < BAD) {
            float s = 0.f;
            for (int d = 0; d < VD; ++d) s += Wq[d * BAD + e] * Wk[d * BAD + f];
            val = s;
        }
    } else if (idx < O_GKK) {
        int j = idx - O_GQQ; int e = j / STR, f = j % STR;
        if (f < BAD && f <= e) {
            float s = 0.f;
            for (int d = 0; d < VD; ++d) s += Wq[d * BAD + e] * Wq[d * BAD + f];
            val = (f == e) ? s : 2.0f * s;
        }
    } else if (idx < O_V1) {
        int j = idx - O_GKK; int e = j / STR, f = j % STR;
        if (f < BAD && f <= e) {
            float s = 0.f;
            for (int d = 0; d < VD; ++d) s += Wk[d * BAD + e] * Wk[d * BAD + f];
            val = (f == e) ? s : 2.0f * s;
        }
    } else if (idx < O_V2) {
        int e = idx - O_V1;
        if (e < BAD) { float s = 0.f; for (int d = 0; d < VD; ++d) s += Wq[d * BAD + e] * bk[d]; val = s; }
    } else if (idx < O_VQ) {
        int e = idx - O_V2;
        if (e < BAD) { float s = 0.f; for (int d = 0; d < VD; ++d) s += Wk[d * BAD + e] * bq[d]; val = s; }
    } else if (idx < O_VK) {
        int e = idx - O_VQ;
        if (e < BAD) { float s = 0.f; for (int d = 0; d < VD; ++d) s += Wq[d * BAD + e] * bq[d]; val = s; }
    } else if (idx < O_C) {
        int e = idx - O_VK;
        if (e < BAD) { float s = 0.f; for (int d = 0; d < VD; ++d) s += Wk[d * BAD + e] * bk[d]; val = s; }
    } else if (idx < O_M) {
        int j = idx - O_C;
        if (j == 0) { float s = 0.f; for (int d = 0; d < VD; ++d) s += bq[d] * bk[d]; val = s; }
        else if (j == 1) { float s = 0.f; for (int d = 0; d < VD; ++d) s += bq[d] * bq[d]; val = s; }
        else if (j == 2) { float s = 0.f; for (int d = 0; d < VD; ++d) s += bk[d] * bk[d]; val = s; }
    } else if (idx < O_MB) {
        int j = idx - O_M; int r = j / STR, c = j % STR;
        if (c < BAD) {
            float s = 0.f;
            for (int k = 0; k < VD; ++k) s += W1[r * VD + k] * Wv[k * BAD + c];
            val = 2.0f * s;
        }
    } else if (idx < O_W2T) {
        int d = idx - O_MB;
        float s = b1[d];
        for (int k = 0; k < VD; ++k) s += W1[d * VD + k] * bv[k];
        val = 2.0f * s;
    } else if (idx < O_B2) {
        int j = idx - O_W2T; int d = j / 16, o = j % 16;
        val = W2[o * VD + d];
    } else if (idx < O_WC1) {
        val = b2[idx - O_B2];
    } else if (idx < O_BC1) {
        int j = idx - O_WC1; int m = j / 84; int r = j % 84; int i = r / STR; int f = r % STR;
        if (f < BAD) val = Wc1[m * (NBK * BAD) + i * BAD + f];
    } else if (idx < O_WC2) {
        int m = idx - O_BC1;
        if (m < CM) val = bc1[m];
    } else if (idx < O_BC2) {
        int j = idx - O_WC2; int o = j / 12, m = j % 12;
        if (m < CM) val = Wc2[o * CM + m];
    } else {
        int o = idx - O_BC2;
        if (o < 3) val = bc2[o];
    }
    ws[idx] = val;
}

// Fused kernel. Phase 1 (per thread = 1 element): attention + conf via the
// s_load/SGPR weight channel (R8, spill-free); a_tilde -> LDS bf16.
// Phase 2 (per wave): MFMA GEMM1(16x16x32, K=32 incl. bias col) -> tanh ->
// LDS transpose -> MFMA GEMM2 (K=128) -> +states+b2 -> store.
// a_tilde LDS stride 40 ushorts (80 B): 16B-aligned, banks (18r+c) -> <=2-way.
// P stride 136 ushorts (272 B): 16B-aligned, banks (4m+c) -> 2-way.
__global__ __launch_bounds__(256) void main_kernel(
    const float* __restrict__ states, const float* __restrict__ action,
    const int* __restrict__ block_id,
    const float* __restrict__ ws, float* __restrict__ out) {
    __shared__ __align__(16) unsigned short At[768 * 40];   // 61440 B
    __shared__ __align__(16) unsigned short P[4 * 16 * 136]; // 17408 B

    int t = threadIdx.x;
    int elem = blockIdx.x * 256 + t;

    const float* st = states + (long)elem * (NBK * SS);
    const float* ac = action + (long)elem * NA;
    const int* bid = block_id + (long)elem * NBK;

    // ---- build ba[3][25] (all indices compile-time) ----
    float ba[NBK * BAD];
    #pragma unroll
    for (int i = 0; i < NBK; ++i) {
        const float4* s4 = (const float4*)(st + i * SS);
        #pragma unroll
        for (int w = 0; w < 4; ++w) {
            float4 v = s4[w];
            ba[i * BAD + w * 4 + 0] = v.x;
            ba[i * BAD + w * 4 + 1] = v.y;
            ba[i * BAD + w * 4 + 2] = v.z;
            ba[i * BAD + w * 4 + 3] = v.w;
        }
        bool sel = (bid[i] == 1);
        #pragma unroll
        for (int c = 0; c < NA; ++c)
            ba[i * BAD + SS + c] = sel ? ac[c] : -1.0f;
    }

    // ---- confidence MLP ----
    {
        float hm[CM];
        #pragma unroll
        for (int m = 0; m < CM; ++m) {
            float s = ws[O_BC1 + m];
            #pragma unroll
            for (int i = 0; i < NBK; ++i)
                #pragma unroll
                for (int f = 0; f < BAD; ++f)
                    s += ws[O_WC1 + m * 84 + i * STR + f] * ba[i * BAD + f];
            hm[m] = fast_sigmoid(s);
        }
        float* op = out + (long)elem * OUTD;
        #pragma unroll
        for (int o = 0; o < 3; ++o) {
            float s = ws[O_BC2 + o];
            #pragma unroll
            for (int m = 0; m < CM; ++m) s += ws[O_WC2 + o * 12 + m] * hm[m];
            op[48 + o] = fast_sigmoid(s);
        }
    }

    // ---- linear score terms ----
    float s1[NBK], s2[NBK], dq[NBK], dk[NBK];
    #pragma unroll
    for (int p = 0; p < NBK; ++p) {
        float a1 = 0.f, a2 = 0.f, aq = 0.f, ak = 0.f;
        #pragma unroll
        for (int e = 0; e < BAD; ++e) {
            float b = ba[p * BAD + e];
            a1 += ws[O_V1 + e] * b;
            a2 += ws[O_V2 + e] * b;
            aq += ws[O_VQ + e] * b;
            ak += ws[O_VK + e] * b;
        }
        s1[p] = a1; s2[p] = a2; dq[p] = aq; dk[p] = ak;
    }
    float c0 = ws[O_C + 0], cq = ws[O_C + 1], ck = ws[O_C + 2];

    // ---- bilinear numerators ----
    float num[NBK][NBK] = {{0.f,0.f,0.f},{0.f,0.f,0.f},{0.f,0.f,0.f}};
    #pragma unroll
    for (int e = 0; e < BAD; ++e) {
        float t0 = 0.f, t1 = 0.f, t2 = 0.f;
        #pragma unroll
        for (int f = 0; f < BAD; ++f) {
            float g = ws[O_GQK + e * STR + f];
            t0 += g * ba[0 * BAD + f];
            t1 += g * ba[1 * BAD + f];
            t2 += g * ba[2 * BAD + f];
        }
        #pragma unroll
        for (int i = 0; i < NBK; ++i) {
            float be = ba[i * BAD + e];
            num[i][0] += be * t0;
            num[i][1] += be * t1;
            num[i][2] += be * t2;
        }
    }

    // ---- quadratic forms via scaled lower triangles ----
    float qn2[NBK] = {0.f, 0.f, 0.f}, kn2[NBK] = {0.f, 0.f, 0.f};
    #pragma unroll
    for (int e = 0; e < BAD; ++e) {
        float pq0 = 0.f, pq1 = 0.f, pq2 = 0.f;
        float pk0 = 0.f, pk1 = 0.f, pk2 = 0.f;
        #pragma unroll
        for (int f = 0; f <= e; ++f) {
            float gq = ws[O_GQQ + e * STR + f];
            float gk = ws[O_GKK + e * STR + f];
            float b0 = ba[0 * BAD + f], b1v = ba[1 * BAD + f], b2v = ba[2 * BAD + f];
            pq0 += gq * b0; pq1 += gq * b1v; pq2 += gq * b2v;
            pk0 += gk * b0; pk1 += gk * b1v; pk2 += gk * b2v;
        }
        qn2[0] += ba[0 * BAD + e] * pq0;
        qn2[1] += ba[1 * BAD + e] * pq1;
        qn2[2] += ba[2 * BAD + e] * pq2;
        kn2[0] += ba[0 * BAD + e] * pk0;
        kn2[1] += ba[1 * BAD + e] * pk1;
        kn2[2] += ba[2 * BAD + e] * pk2;
    }
    #pragma unroll
    for (int p = 0; p < NBK; ++p) {
        qn2[p] += 2.0f * dq[p] + cq;
        kn2[p] += 2.0f * dk[p] + ck;
    }

    // ---- softmax over j ----
    float att[NBK][NBK];
    {
        float kn[NBK];
        #pragma unroll
        for (int j = 0; j < NBK; ++j) kn[j] = __builtin_amdgcn_sqrtf(fmaxf(kn2[j], 0.0f));
        #pragma unroll
        for (int i = 0; i < NBK; ++i) {
            float qn = __builtin_amdgcn_sqrtf(fmaxf(qn2[i], 0.0f));
            float dv[NBK];
            #pragma unroll
            for (int j = 0; j < NBK; ++j)
                dv[j] = (num[i][j] + s1[i] + s2[j] + c0) *
                        __builtin_amdgcn_rcpf(fmaxf(qn * kn[j], EPS));
            float mx = fmaxf(dv[0], fmaxf(dv[1], dv[2]));
            float e0 = __expf(dv[0] - mx);
            float e1 = __expf(dv[1] - mx);
            float e2 = __expf(dv[2] - mx);
            float inv = __builtin_amdgcn_rcpf(e0 + e1 + e2);
            att[i][0] = e0 * inv;
            att[i][1] = e1 * inv;
            att[i][2] = e2 * inv;
        }
    }

    // ---- a_tilde (in place) ----
    #pragma unroll
    for (int e = 0; e < BAD; ++e) {
        float b0 = ba[0 * BAD + e], b1v = ba[1 * BAD + e], b2v = ba[2 * BAD + e];
        ba[0 * BAD + e] = att[0][0] * b0 + att[0][1] * b1v + att[0][2] * b2v;
        ba[1 * BAD + e] = att[1][0] * b0 + att[1][1] * b1v + att[1][2] * b2v;
        ba[2 * BAD + e] = att[2][0] * b0 + att[2][1] * b1v + att[2][2] * b2v;
    }

    // ---- write a_tilde rows to LDS as bf16 (col 25 = 1.0 bias, 26-31 = 0) ----
    #pragma unroll
    for (int i = 0; i < NBK; ++i) {
        unsigned int* dst = (unsigned int*)&At[(t * 3 + i) * 40];
        #pragma unroll
        for (int pr = 0; pr < 12; ++pr)
            dst[pr] = (unsigned int)f2bf(ba[i * BAD + 2 * pr]) |
                      ((unsigned int)f2bf(ba[i * BAD + 2 * pr + 1]) << 16);
        dst[12] = (unsigned int)f2bf(ba[i * BAD + 24]) | (0x3F80u << 16);
        dst[13] = 0u; dst[14] = 0u; dst[15] = 0u;
    }
    __syncthreads();

    // ================= phase 2: MFMA =================
    int lane = t & 63, w = t >> 6;
    int m = lane & 15, q = lane >> 4;
    const short8* pkM = (const short8*)(ws + O_PKM);
    const short8* pkW2 = (const short8*)(ws + O_PKW2);
    float b2v = ws[O_B2 + m];   // exact fp32 bias, col o = m
    long blockbase = (long)blockIdx.x * 256;

    for (int tt = 0; tt < 12; ++tt) {
        int tile = w * 12 + tt;            // rows tile*16 .. +15
        // GEMM1: A-frag = At[tile*16+m][q*8 .. +8]
        short8 af = *(const short8*)&At[(tile * 16 + m) * 40 + q * 8];
        floatx4 acc[8];
        #pragma unroll
        for (int nt = 0; nt < 8; ++nt) {
            floatx4 z = {0.f, 0.f, 0.f, 0.f};
            acc[nt] = __builtin_amdgcn_mfma_f32_16x16x32_bf16(af, pkM[nt * 64 + lane], z, 0, 0, 0);
        }
        // tanh epilogue, write P (D layout: row=q*4+r, col=nt*16+m)
        #pragma unroll
        for (int nt = 0; nt < 8; ++nt)
            #pragma unroll
            for (int r = 0; r < 4; ++r) {
                float v = fmaf(-2.0f, __builtin_amdgcn_rcpf(1.0f + __expf(acc[nt][r])), 1.0f);
                P[w * 2176 + (q * 4 + r) * 136 + nt * 16 + m] = f2bf(v);
            }
        // GEMM2: A2[m][k] = P[m][kt*32 + q*8 + j]
        floatx4 acc2 = {0.f, 0.f, 0.f, 0.f};
        #pragma unroll
        for (int kt = 0; kt < 4; ++kt) {
            short8 a2 = *(const short8*)&P[w * 2176 + m * 136 + kt * 32 + q * 8];
            acc2 = __builtin_amdgcn_mfma_f32_16x16x32_bf16(a2, pkW2[kt * 64 + lane], acc2, 0, 0, 0);
        }
        // epilogue: + states + b2, store (D2: row=q*4+r, col o=m)
        #pragma unroll
        for (int r = 0; r < 4; ++r) {
            int lrow = tile * 16 + q * 4 + r;          // 0..767
            int et = lrow / 3, i = lrow - et * 3;      // const-div magic
            long ge = blockbase + et;
            float base = states[ge * 48 + i * 16 + m];
            out[ge * OUTD + i * 16 + m] = acc2[r] + base + b2v;
        }
    }
}

extern "C" void kernel_launch(void* const* d_in, const int* in_sizes, int n_in,
                              void* d_out, int out_size, void* d_ws, size_t ws_size,
                              hipStream_t stream) {
    const float* states = (const float*)d_in[0];
    const float* action = (const float*)d_in[1];
    const int* block_id = (const int*)d_in[2];
    const float* Wq = (const float*)d_in[3];
    const float* bq = (const float*)d_in[4];
    const float* Wk = (const float*)d_in[5];
    const float* bk = (const float*)d_in[6];
    const float* Wv = (const float*)d_in[7];
    const float* bv = (const float*)d_in[8];
    const float* W1 = (const float*)d_in[9];
    const float* b1 = (const float*)d_in[10];
    const float* W2 = (const float*)d_in[11];
    const float* b2 = (const float*)d_in[12];
    const float* Wc1 = (const float*)d_in[13];
    const float* bc1 = (const float*)d_in[14];
    const float* Wc2 = (const float*)d_in[15];
    const float* bc2 = (const float*)d_in[16];
    float* out = (float*)d_out;
    float* ws = (float*)d_ws;

    hipLaunchKernelGGL(prep_kernel, dim3((TOT_IDX + 255) / 256), dim3(256), 0, stream,
                       Wq, bq, Wk, bk, Wv, bv, W1, b1, W2, b2, Wc1, bc1, Wc2, bc2, ws);
    hipLaunchKernelGGL(main_kernel, dim3(BTOT / 256), dim3(256), 0, stream,
                       states, action, block_id, ws, out);
}